// Round 1
// baseline (275.709 us; speedup 1.0000x reference)
//
#include <hip/hip_runtime.h>
#include <stdint.h>
#include <stddef.h>

// MixedScaleAttention (b=2048, nq=64, nk=128/group, groups sd={32,32,64}, d=16)
// One block per batch, 512 threads (8 waves). Fully fused in LDS.
// bf16 MFMA (16x16x32) with f32 accumulate. Weights pre-converted to bf16 in d_ws.
//
// Assumptions (revisit if absmax fails):
//  - key_masks (jax bool) is pushed as int32 ("integer -> const int*")
//  - MFMA frag layout: A[m][k]: m=lane&15, k=(lane>>4)*8+i ; B[k][n]: n=lane&15,
//    k=(lane>>4)*8+i ; C/D: col=lane&15, row=(lane>>4)*4+reg  (guide m89/m91)
//  - static __shared__ 80KB OK on gfx950 (guide m201 example uses 128KB)

#define B_ 2048
#define E_ 128

typedef __attribute__((ext_vector_type(8))) short bf8;
typedef __attribute__((ext_vector_type(4))) short bf4;
typedef __attribute__((ext_vector_type(4))) float f4;

__device__ __forceinline__ unsigned short f2bf(float f) {
  union { float f; uint32_t u; } v; v.f = f;
  return (unsigned short)((v.u + 0x7fffu + ((v.u >> 16) & 1u)) >> 16);
}

struct Params {
  const float* query;
  const float* keys;
  const int* km;
  const float* rpb[3];
  const float* bq[3];
  const float* bkv[3];
  const float* bp[3];
  const unsigned short* wq[3];
  const unsigned short* wkv[3];
  const unsigned short* wp[3];
  float* out;
};

struct WC { const float* src[9]; unsigned short* dst; };

// convert the 9 weight matrices (f32) to bf16 into ws
__global__ void conv_w(WC w) {
  int i = blockIdx.x * 256 + threadIdx.x;
  if (i >= 24576) return;
  const int off[10] = {0, 1024, 3072, 4096, 5120, 7168, 8192, 12288, 20480, 24576};
  int r = 0;
  while (i >= off[r + 1]) ++r;
  w.dst[i] = f2bf(w.src[r][i - off[r]]);
}

// swizzled byte offset within a row-major LDS tile (row stride in bytes).
// XOR bits 4-6 with row&7: keeps 8B/16B alignment, kills stride-128/256 bank conflicts.
__device__ __forceinline__ int swz(int row, int cb, int stride) {
  return row * stride + (cb ^ ((row & 7) << 4));
}

template <int SD, int NH, int G>
__device__ __forceinline__ void group_body(const Params& p, int b, int tid,
                                           unsigned char* R1,   // Kst [128][64]bf16 (16KB)
                                           unsigned char* R2,   // kg [128][64] -> P0 [64][128] (16KB)
                                           unsigned char* P1b,  // q_g [64][64] -> P1 [64][128] (16KB)
                                           unsigned char* QstB, // Qst [64][64] (8KB)
                                           unsigned char* VtB,  // Vt [64][128] (16KB)
                                           unsigned char* XstB) // Xst [64][64] (8KB)
{
  constexpr int START = (G == 2) ? 64 : 32 * G;
  const int lane = tid & 63;
  const int wave = tid >> 6;
  const int l15 = lane & 15;
  const int lg = lane >> 4;

  // ---------- stage q slice (into P1b) and key slice (into R2), f32 -> bf16 ----------
  {
    constexpr int TPR = SD / 8; // threads per q-row (4 or 8)
    int row = tid / TPR;
    int cid = tid % TPR;
    if (row < 64) {
      const float* src = p.query + ((size_t)row * B_ + b) * E_ + START + cid * 8;
      float4 v0 = *(const float4*)(src);
      float4 v1 = *(const float4*)(src + 4);
      bf4 s0 = {(short)f2bf(v0.x), (short)f2bf(v0.y), (short)f2bf(v0.z), (short)f2bf(v0.w)};
      bf4 s1 = {(short)f2bf(v1.x), (short)f2bf(v1.y), (short)f2bf(v1.z), (short)f2bf(v1.w)};
      int cb = cid * 16;
      *(bf4*)(P1b + swz(row, cb, 128)) = s0;
      *(bf4*)(P1b + swz(row, cb + 8, 128)) = s1;
    }
    int krow = tid >> 2;
    int kc0 = (tid & 3) * (SD / 4);
    const float* ksrc = p.keys + ((size_t)(G * 128 + krow) * B_ + b) * E_ + START + kc0;
#pragma unroll
    for (int jj = 0; jj < SD / 4; jj += 8) {
      float4 v0 = *(const float4*)(ksrc + jj);
      float4 v1 = *(const float4*)(ksrc + jj + 4);
      bf4 s0 = {(short)f2bf(v0.x), (short)f2bf(v0.y), (short)f2bf(v0.z), (short)f2bf(v0.w)};
      bf4 s1 = {(short)f2bf(v1.x), (short)f2bf(v1.y), (short)f2bf(v1.z), (short)f2bf(v1.w)};
      int cb = (kc0 + jj) * 2;
      *(bf4*)(R2 + swz(krow, cb, 128)) = s0;
      *(bf4*)(R2 + swz(krow, cb + 8, 128)) = s1;
    }
  }
  __syncthreads();

  // ---------- fused Q-proj + KV-proj (job-parallel over 8 waves) ----------
  {
    constexpr int QNT = SD / 16;      // 2 or 4
    constexpr int QJOBS = 4 * QNT;    // 8 or 16
    constexpr int KNT = 2 * SD / 16;  // 4 or 8
    constexpr int KVJOBS = 8 * KNT;   // 32 or 64
    for (int j = wave; j < QJOBS + KVJOBS; j += 8) {
      if (j < QJOBS) {
        int mt = j / QNT, nt = j % QNT;
        f4 acc = {0.f, 0.f, 0.f, 0.f};
#pragma unroll
        for (int kk = 0; kk < SD; kk += 32) {
          bf8 a = *(const bf8*)(P1b + swz(mt * 16 + l15, (kk + lg * 8) * 2, 128));
          bf8 w = *(const bf8*)(&p.wq[G][(nt * 16 + l15) * SD + kk + lg * 8]);
          acc = __builtin_amdgcn_mfma_f32_16x16x32_bf16(a, w, acc, 0, 0, 0);
        }
        int c = nt * 16 + l15;
        float bias = p.bq[G][c];
        int q0 = mt * 16 + lg * 4;
#pragma unroll
        for (int r = 0; r < 4; ++r)
          *(unsigned short*)(QstB + swz(q0 + r, c * 2, 128)) = f2bf((acc[r] + bias) * 0.25f);
      } else {
        int jj = j - QJOBS;
        int mt = jj / KNT, nt = jj % KNT;
        f4 acc = {0.f, 0.f, 0.f, 0.f};
#pragma unroll
        for (int kk = 0; kk < SD; kk += 32) {
          bf8 a = *(const bf8*)(R2 + swz(mt * 16 + l15, (kk + lg * 8) * 2, 128));
          bf8 w = *(const bf8*)(&p.wkv[G][(nt * 16 + l15) * SD + kk + lg * 8]);
          acc = __builtin_amdgcn_mfma_f32_16x16x32_bf16(a, w, acc, 0, 0, 0);
        }
        int n = nt * 16 + l15;
        float bias = p.bkv[G][n];
        int key0 = mt * 16 + lg * 4;
        if (n < SD) { // K part -> Kst[key][n]
#pragma unroll
          for (int r = 0; r < 4; ++r)
            *(unsigned short*)(R1 + swz(key0 + r, n * 2, 128)) = f2bf(acc[r] + bias);
        } else {      // V part, transposed -> Vt[d][key]
          int d = n - SD;
          bf4 s = {(short)f2bf(acc[0] + bias), (short)f2bf(acc[1] + bias),
                   (short)f2bf(acc[2] + bias), (short)f2bf(acc[3] + bias)};
          *(bf4*)(VtB + swz(d, key0 * 2, 256)) = s;
        }
      }
    }
  }
  __syncthreads();

  // ---------- key-mask bias (per lane, one value per N-tile) ----------
  float kb[8];
#pragma unroll
  for (int nt = 0; nt < 8; ++nt)
    kb[nt] = p.km[(size_t)b * 384 + G * 128 + nt * 16 + l15] ? -100.0f : 0.0f;

  // ---------- attention: two heads concurrently (wave-halves), NH/2 passes ----------
  for (int hp = 0; hp < NH / 2; ++hp) {
    const int head = hp * 2 + (wave >> 2);
    const int mt = wave & 3;
    unsigned char* Pb = (wave >> 2) ? P1b : R2;

    // QK^T (K-dim 16 zero-padded to 32: lanes with lg>=2 supply zeros)
    f4 s[8];
#pragma unroll
    for (int nt = 0; nt < 8; ++nt) s[nt] = (f4){0.f, 0.f, 0.f, 0.f};
    {
      bf8 zz = {0, 0, 0, 0, 0, 0, 0, 0};
      bf8 afrag = zz;
      if (lg < 2)
        afrag = *(const bf8*)(QstB + swz(mt * 16 + l15, head * 32 + lg * 16, 128));
#pragma unroll
      for (int nt = 0; nt < 8; ++nt) {
        bf8 kfrag = zz;
        if (lg < 2)
          kfrag = *(const bf8*)(R1 + swz(nt * 16 + l15, head * 32 + lg * 16, 128));
        s[nt] = __builtin_amdgcn_mfma_f32_16x16x32_bf16(afrag, kfrag, s[nt], 0, 0, 0);
      }
    }
    // + rpb + mask bias, then in-register softmax over 128 keys
    const float* rpbh = p.rpb[G] + head * (64 * 128);
    const int q0 = mt * 16 + lg * 4;
#pragma unroll
    for (int nt = 0; nt < 8; ++nt)
#pragma unroll
      for (int r = 0; r < 4; ++r)
        s[nt][r] += rpbh[(q0 + r) * 128 + nt * 16 + l15] + kb[nt];

    float inv[4];
    {
      float mx[4], sm[4];
#pragma unroll
      for (int r = 0; r < 4; ++r) {
        float m0 = s[0][r];
#pragma unroll
        for (int nt = 1; nt < 8; ++nt) m0 = fmaxf(m0, s[nt][r]);
#pragma unroll
        for (int d = 1; d <= 8; d <<= 1) m0 = fmaxf(m0, __shfl_xor(m0, d, 64));
        mx[r] = m0;
        sm[r] = 0.f;
      }
#pragma unroll
      for (int nt = 0; nt < 8; ++nt)
#pragma unroll
        for (int r = 0; r < 4; ++r) {
          float e = __expf(s[nt][r] - mx[r]);
          s[nt][r] = e;
          sm[r] += e;
        }
#pragma unroll
      for (int r = 0; r < 4; ++r) {
        float t = sm[r];
#pragma unroll
        for (int d = 1; d <= 8; d <<= 1) t += __shfl_xor(t, d, 64);
        inv[r] = 1.0f / t;
      }
    }
    // write P (bf16) to this half's P buffer
#pragma unroll
    for (int nt = 0; nt < 8; ++nt)
#pragma unroll
      for (int r = 0; r < 4; ++r)
        *(unsigned short*)(Pb + swz(q0 + r, (nt * 16 + l15) * 2, 256)) = f2bf(s[nt][r] * inv[r]);
    __syncthreads();

    // PV: X_h = P @ V_h  (A from P, B^T from Vt[d][key])
    {
      f4 x = {0.f, 0.f, 0.f, 0.f};
#pragma unroll
      for (int kk = 0; kk < 4; ++kk) {
        bf8 pa = *(const bf8*)(Pb + swz(mt * 16 + l15, kk * 64 + lg * 16, 256));
        bf8 vb = *(const bf8*)(VtB + swz(head * 16 + l15, kk * 64 + lg * 16, 256));
        x = __builtin_amdgcn_mfma_f32_16x16x32_bf16(pa, vb, x, 0, 0, 0);
      }
#pragma unroll
      for (int r = 0; r < 4; ++r)
        *(unsigned short*)(XstB + swz(q0 + r, (head * 16 + l15) * 2, 128)) = f2bf(x[r]);
    }
    __syncthreads();
  }

  // ---------- out projection: out[q][b][START+c] = Xst @ wp^T + bp ----------
  {
    constexpr int ONT = SD / 16;
    for (int j = wave; j < 4 * ONT; j += 8) {
      int mt = j / ONT, nt = j % ONT;
      f4 acc = {0.f, 0.f, 0.f, 0.f};
#pragma unroll
      for (int kk = 0; kk < SD; kk += 32) {
        bf8 a = *(const bf8*)(XstB + swz(mt * 16 + l15, (kk + lg * 8) * 2, 128));
        bf8 w = *(const bf8*)(&p.wp[G][(nt * 16 + l15) * SD + kk + lg * 8]);
        acc = __builtin_amdgcn_mfma_f32_16x16x32_bf16(a, w, acc, 0, 0, 0);
      }
      int c = nt * 16 + l15;
      float bias = p.bp[G][c];
      int q0 = mt * 16 + lg * 4;
#pragma unroll
      for (int r = 0; r < 4; ++r)
        p.out[((size_t)(q0 + r) * B_ + b) * E_ + START + c] = acc[r] + bias;
    }
  }
  __syncthreads();
}

__launch_bounds__(512, 4)
__global__ void msa_main(Params p) {
  __shared__ __align__(16) unsigned char R1[16384];
  __shared__ __align__(16) unsigned char R2[16384];
  __shared__ __align__(16) unsigned char P1b[16384];
  __shared__ __align__(16) unsigned char QstB[8192];
  __shared__ __align__(16) unsigned char VtB[16384];
  __shared__ __align__(16) unsigned char XstB[8192];
  const int b = blockIdx.x;
  const int tid = threadIdx.x;
  group_body<32, 2, 0>(p, b, tid, R1, R2, P1b, QstB, VtB, XstB);
  group_body<32, 2, 1>(p, b, tid, R1, R2, P1b, QstB, VtB, XstB);
  group_body<64, 4, 2>(p, b, tid, R1, R2, P1b, QstB, VtB, XstB);
}

extern "C" void kernel_launch(void* const* d_in, const int* in_sizes, int n_in,
                              void* d_out, int out_size, void* d_ws, size_t ws_size,
                              hipStream_t stream) {
  (void)in_sizes; (void)n_in; (void)out_size;
  Params p;
  p.query = (const float*)d_in[0];
  p.keys = (const float*)d_in[1];
  p.km = (const int*)d_in[2];
  unsigned short* wbf = (unsigned short*)d_ws;
  const int base[3] = {3, 10, 17};
  const int woff[3][3] = {{0, 1024, 3072}, {4096, 5120, 7168}, {8192, 12288, 20480}};
  WC wc;
  for (int g = 0; g < 3; ++g) {
    p.rpb[g] = (const float*)d_in[base[g] + 0];
    p.bq[g] = (const float*)d_in[base[g] + 2];
    p.bkv[g] = (const float*)d_in[base[g] + 4];
    p.bp[g] = (const float*)d_in[base[g] + 6];
    p.wq[g] = wbf + woff[g][0];
    p.wkv[g] = wbf + woff[g][1];
    p.wp[g] = wbf + woff[g][2];
    wc.src[g * 3 + 0] = (const float*)d_in[base[g] + 1]; // wq
    wc.src[g * 3 + 1] = (const float*)d_in[base[g] + 3]; // wkv
    wc.src[g * 3 + 2] = (const float*)d_in[base[g] + 5]; // wp
  }
  wc.dst = wbf;
  p.out = (float*)d_out;

  if (ws_size >= 24576 * sizeof(unsigned short))
    conv_w<<<96, 256, 0, stream>>>(wc);
  msa_main<<<2048, 512, 0, stream>>>(p);
}

// Round 2
// 270.072 us; speedup vs baseline: 1.0209x; 1.0209x over previous
//
#include <hip/hip_runtime.h>
#include <stdint.h>
#include <stddef.h>

// MixedScaleAttention round 2: 32x32x16 MFMA, swapped QK^T, in-register softmax,
// permlane32_swap P->PV, no input staging, 5 phases / 4 barriers, 50.7KB LDS.

#define B_ 2048
#define E_ 128

typedef __attribute__((ext_vector_type(8))) short bf8;
typedef __attribute__((ext_vector_type(16))) float f16f;
typedef __attribute__((ext_vector_type(2))) int iv2;

#define ZERO16 ((f16f){0.f,0.f,0.f,0.f,0.f,0.f,0.f,0.f,0.f,0.f,0.f,0.f,0.f,0.f,0.f,0.f})

__device__ __forceinline__ unsigned short f2bf(float f) {
  union { float f; uint32_t u; } v; v.f = f;
  return (unsigned short)((v.u + 0x7fffu + ((v.u >> 16) & 1u)) >> 16);
}

__device__ __forceinline__ unsigned int cvtpk(float lo, float hi) {
  unsigned int r;
  asm("v_cvt_pk_bf16_f32 %0, %1, %2" : "=v"(r) : "v"(lo), "v"(hi));
  return r;
}

union FR { unsigned long long q[2]; unsigned int u[4]; bf8 v; };

// 8B-granular XOR swizzle: byte col ^ ((row&15)<<3). All reads are 2x b64.
__device__ __forceinline__ bf8 lds_frag(const unsigned char* t, int row, int stride, int colb) {
  FR f;
  const unsigned char* base = t + row * stride;
  const int x = (row & 15) << 3;
  f.q[0] = *(const unsigned long long*)(base + (colb ^ x));
  f.q[1] = *(const unsigned long long*)(base + ((colb + 8) ^ x));
  return f.v;
}

__device__ __forceinline__ void lds_w16(unsigned char* t, int row, int stride, int colb, unsigned short v) {
  *(unsigned short*)(t + row * stride + (colb ^ ((row & 15) << 3))) = v;
}

__device__ __forceinline__ bf8 gfrag(const float* p) {
  float4 a = *(const float4*)p;
  float4 b = *(const float4*)(p + 4);
  bf8 r;
  r[0] = (short)f2bf(a.x); r[1] = (short)f2bf(a.y); r[2] = (short)f2bf(a.z); r[3] = (short)f2bf(a.w);
  r[4] = (short)f2bf(b.x); r[5] = (short)f2bf(b.y); r[6] = (short)f2bf(b.z); r[7] = (short)f2bf(b.w);
  return r;
}

struct P2 {
  const float* query;
  const float* keys;
  const int* km;
  const float* rpb[3];
  const float* rpbT;  // [8 heads][128 key][64 q] f32, may be null
  const unsigned short* wqP[3];
  const unsigned short* wkvP[3];
  const unsigned short* wpP[3];
  const float* bq[3];
  const float* bkv[3];
  const float* bp[3];
  float* out;
};

// KV projection job: one 32-key tile (m-tile), nt range of output-dim tiles.
template <int SD>
__device__ __forceinline__ void do_kv_job(const P2& p, int b, int grow_base, int klocal_base,
                                          int colbase, const unsigned short* wkvP, const float* bkv,
                                          unsigned char* Kst, unsigned char* Vt,
                                          int kdim_base, int vdim_base, int nt0, int nt1, int lane) {
  constexpr int KT = SD / 16;
  const int l31 = lane & 31, hi = lane >> 5;
  bf8 afr[KT];
  const float* ap = p.keys + ((size_t)(grow_base + l31) * B_ + b) * E_ + colbase + hi * 8;
#pragma unroll
  for (int kk = 0; kk < KT; ++kk) afr[kk] = gfrag(ap + kk * 16);
  for (int nt = nt0; nt < nt1; ++nt) {
    f16f acc = ZERO16;
#pragma unroll
    for (int kk = 0; kk < KT; ++kk) {
      bf8 w = *(const bf8*)(wkvP + (((size_t)(nt * KT + kk)) * 64 + lane) * 8);
      acc = __builtin_amdgcn_mfma_f32_32x32x16_bf16(afr[kk], w, acc, 0, 0, 0);
    }
    int n = nt * 32 + l31;
    float bias = bkv[n];
    if (nt * 32 < SD) {  // K half (uniform per nt)
      int col = (kdim_base + n) * 2;
#pragma unroll
      for (int r = 0; r < 16; ++r) {
        int row = klocal_base + (r & 3) + 8 * (r >> 2) + 4 * hi;
        lds_w16(Kst, row, 128, col, f2bf(acc[r] + bias));
      }
    } else {             // V half -> transposed Vt[d][key]
      int d = vdim_base + n - SD;
#pragma unroll
      for (int r = 0; r < 16; ++r) {
        int key = klocal_base + (r & 3) + 8 * (r >> 2) + 4 * hi;
        lds_w16(Vt, d, 256, key * 2, f2bf(acc[r] + bias));
      }
    }
  }
}

template <int SD>
__device__ __forceinline__ void do_q_job(const P2& p, int b, int qt, int colbase,
                                         const unsigned short* wqP, const float* bq,
                                         unsigned char* Qst, int qdim_base, int nt0, int nt1, int lane) {
  constexpr int KT = SD / 16;
  const int l31 = lane & 31, hi = lane >> 5;
  bf8 afr[KT];
  const float* ap = p.query + ((size_t)(qt * 32 + l31) * B_ + b) * E_ + colbase + hi * 8;
#pragma unroll
  for (int kk = 0; kk < KT; ++kk) afr[kk] = gfrag(ap + kk * 16);
  for (int nt = nt0; nt < nt1; ++nt) {
    f16f acc = ZERO16;
#pragma unroll
    for (int kk = 0; kk < KT; ++kk) {
      bf8 w = *(const bf8*)(wqP + (((size_t)(nt * KT + kk)) * 64 + lane) * 8);
      acc = __builtin_amdgcn_mfma_f32_32x32x16_bf16(afr[kk], w, acc, 0, 0, 0);
    }
    int n = nt * 32 + l31;
    float bias = bq[n];
    int col = (qdim_base + n) * 2;
#pragma unroll
    for (int r = 0; r < 16; ++r) {
      int row = qt * 32 + (r & 3) + 8 * (r >> 2) + 4 * hi;
      lds_w16(Qst, row, 128, col, f2bf((acc[r] + bias) * 0.25f));  // fold softmax scale
    }
  }
}

template <int SD>
__device__ __forceinline__ void do_out_job(const P2& p, const unsigned char* Xst, int xdim_base,
                                           int qt, int nt, const unsigned short* wpP, const float* bp,
                                           int b, int colbase, int lane) {
  constexpr int KT = SD / 16;
  const int l31 = lane & 31, hi = lane >> 5;
  f16f acc = ZERO16;
#pragma unroll
  for (int kk = 0; kk < KT; ++kk) {
    bf8 a = lds_frag(Xst, qt * 32 + l31, 128, (xdim_base + kk * 16 + hi * 8) * 2);
    bf8 w = *(const bf8*)(wpP + (((size_t)(nt * KT + kk)) * 64 + lane) * 8);
    acc = __builtin_amdgcn_mfma_f32_32x32x16_bf16(a, w, acc, 0, 0, 0);
  }
  int c = colbase + nt * 32 + l31;
  float bias = bp[nt * 32 + l31];
#pragma unroll
  for (int r = 0; r < 16; ++r) {
    int q = qt * 32 + (r & 3) + 8 * (r >> 2) + 4 * hi;
    p.out[((size_t)q * B_ + b) * E_ + c] = acc[r] + bias;  // 128B-contiguous per 32 lanes
  }
}

// One (group,head,qt) attention job: swapped QK^T -> in-register softmax -> PV.
__device__ __forceinline__ void do_attn_job(const P2& p, const unsigned char* Kst,
                                            const unsigned char* Qst, const unsigned char* Vt,
                                            unsigned char* Xst, const float* kmf,
                                            int dimcol, int km_base, int hh, const float* rpb_orig,
                                            int qt, int lane) {
  const int l31 = lane & 31, hi = lane >> 5;
  f16f s[4];
#pragma unroll
  for (int kt = 0; kt < 4; ++kt) {
    bf8 kf = lds_frag(Kst, kt * 32 + l31, 128, (dimcol + hi * 8) * 2);
    bf8 qf = lds_frag(Qst, qt * 32 + l31, 128, (dimcol + hi * 8) * 2);
    f16f z = ZERO16;
    s[kt] = __builtin_amdgcn_mfma_f32_32x32x16_bf16(kf, qf, z, 0, 0, 0);  // S^T[key][q]
  }
  // + rpb + mask bias (S^T layout: col=q=l31, row=key pattern)
  if (p.rpbT) {
    const float* rt = p.rpbT + (size_t)hh * 8192 + qt * 32 + l31;
#pragma unroll
    for (int kt = 0; kt < 4; ++kt)
#pragma unroll
      for (int r = 0; r < 16; ++r) {
        int krow = kt * 32 + (r & 3) + 8 * (r >> 2) + 4 * hi;
        s[kt][r] += rt[(size_t)krow * 64] + kmf[km_base + krow];
      }
  } else {
    const float* ro = rpb_orig + (qt * 32 + l31) * 128;
#pragma unroll
    for (int kt = 0; kt < 4; ++kt)
#pragma unroll
      for (int r = 0; r < 16; ++r) {
        int krow = kt * 32 + (r & 3) + 8 * (r >> 2) + 4 * hi;
        s[kt][r] += ro[krow] + kmf[km_base + krow];
      }
  }
  // softmax over keys for column q=l31 (this lane + xor-32 partner hold all 128)
  float mx = s[0][0];
#pragma unroll
  for (int kt = 0; kt < 4; ++kt)
#pragma unroll
    for (int r = 0; r < 16; ++r) mx = fmaxf(mx, s[kt][r]);
  mx = fmaxf(mx, __shfl_xor(mx, 32));
  float sum = 0.f;
#pragma unroll
  for (int kt = 0; kt < 4; ++kt)
#pragma unroll
    for (int r = 0; r < 16; ++r) {
      float e = __expf(s[kt][r] - mx);
      s[kt][r] = e;
      sum += e;
    }
  sum += __shfl_xor(sum, 32);
  const float inv = 1.0f / sum;

  // pack P to bf16 and redistribute into PV A-frags; PV accumulate
  f16f o = ZERO16;
  const int vrow = dimcol + (l31 & 15);
#pragma unroll
  for (int kt = 0; kt < 4; ++kt) {
    unsigned int pk[8];
#pragma unroll
    for (int j = 0; j < 8; ++j) pk[j] = cvtpk(s[kt][2 * j] * inv, s[kt][2 * j + 1] * inv);
#pragma unroll
    for (int tt = 0; tt < 2; ++tt) {
      FR af;
#if __has_builtin(__builtin_amdgcn_permlane32_swap)
      iv2 w02 = __builtin_amdgcn_permlane32_swap((int)pk[4 * tt], (int)pk[4 * tt + 2], false, false);
      iv2 w13 = __builtin_amdgcn_permlane32_swap((int)pk[4 * tt + 1], (int)pk[4 * tt + 3], false, false);
      af.u[0] = (unsigned)w02[0]; af.u[1] = (unsigned)w13[0];
      af.u[2] = (unsigned)w02[1]; af.u[3] = (unsigned)w13[1];
#else
      unsigned a0 = pk[4 * tt], a1 = pk[4 * tt + 1], b0 = pk[4 * tt + 2], b1 = pk[4 * tt + 3];
      unsigned pa0 = (unsigned)__shfl_xor((int)a0, 32);
      unsigned pa1 = (unsigned)__shfl_xor((int)a1, 32);
      unsigned pb0 = (unsigned)__shfl_xor((int)b0, 32);
      unsigned pb1 = (unsigned)__shfl_xor((int)b1, 32);
      af.u[0] = hi ? pb0 : a0; af.u[1] = hi ? pb1 : a1;
      af.u[2] = hi ? b0 : pa0; af.u[3] = hi ? b1 : pa1;
#endif
      int t = kt * 2 + tt;
      bf8 vf = lds_frag(Vt, vrow, 256, (t * 16 + hi * 8) * 2);
      o = __builtin_amdgcn_mfma_f32_32x32x16_bf16(af.v, vf, o, 0, 0, 0);  // X[q][d]
    }
  }
  if (l31 < 16) {
#pragma unroll
    for (int r = 0; r < 16; ++r) {
      int q = qt * 32 + (r & 3) + 8 * (r >> 2) + 4 * hi;
      lds_w16(Xst, q, 128, (dimcol + l31) * 2, f2bf(o[r]));
    }
  }
}

__launch_bounds__(512, 4)
__global__ void msa2(P2 p) {
  __shared__ __align__(16) unsigned char Qst[8192];    // [64 q][64 dim] bf16
  __shared__ __align__(16) unsigned char Kst[16384];   // [128 key][64 dim] bf16
  __shared__ __align__(16) unsigned char Vt[16384];    // [64 d][128 key] bf16
  __shared__ __align__(16) unsigned char Xst[8192];    // [64 q][64 dim] bf16
  __shared__ float kmf[384];
  const int b = blockIdx.x;
  const int tid = threadIdx.x;
  const int wave = tid >> 6;
  const int lane = tid & 63;

  // ---- phase 1: projections for groups 0,1 (+ key-mask bias stage) ----
  if (tid < 384) kmf[tid] = p.km[(size_t)b * 384 + tid] ? -100.0f : 0.0f;
  {
    int g = wave >> 2, mt = wave & 3;
    do_kv_job<32>(p, b, g * 128 + mt * 32, mt * 32, g * 32, p.wkvP[g], p.bkv[g],
                  Kst, Vt, g * 32, g * 32, 0, 2, lane);
    if (wave < 4) {
      int qg = wave >> 1, qt = wave & 1;
      do_q_job<32>(p, b, qt, qg * 32, p.wqP[qg], p.bq[qg], Qst, qg * 32, 0, 1, lane);
    }
  }
  __syncthreads();
  // ---- phase 2: attention groups 0,1 (8 jobs) ----
  {
    int g = wave >> 2, head = (wave >> 1) & 1, qt = wave & 1;
    do_attn_job(p, Kst, Qst, Vt, Xst, kmf, g * 32 + head * 16, g * 128,
                g * 2 + head, p.rpb[g] + head * 8192, qt, lane);
  }
  __syncthreads();
  // ---- phase 3: out-proj groups 0,1 overlapped with projections group 2 ----
  {
    int mt = wave >> 1, nth = wave & 1;
    do_kv_job<64>(p, b, 256 + mt * 32, mt * 32, 64, p.wkvP[2], p.bkv[2],
                  Kst, Vt, 0, 0, nth * 2, nth * 2 + 2, lane);
    if (wave < 4) {
      int g = wave >> 1, qt = wave & 1;
      do_out_job<32>(p, Xst, g * 32, qt, 0, p.wpP[g], p.bp[g], b, g * 32, lane);
    } else {
      int qt = (wave >> 1) & 1, nt = wave & 1;
      do_q_job<64>(p, b, qt, 64, p.wqP[2], p.bq[2], Qst, 0, nt, nt + 1, lane);
    }
  }
  __syncthreads();
  // ---- phase 4: attention group 2 (8 jobs) ----
  {
    int head = wave >> 1, qt = wave & 1;
    do_attn_job(p, Kst, Qst, Vt, Xst, kmf, head * 16, 256,
                4 + head, p.rpb[2] + head * 8192, qt, lane);
  }
  __syncthreads();
  // ---- phase 5: out-proj group 2 ----
  if (wave < 4) {
    int qt = wave >> 1, nt = wave & 1;
    do_out_job<64>(p, Xst, 0, qt, nt, p.wpP[2], p.bp[2], b, 64, lane);
  }
}

// ---- pre-kernel: pack weights to MFMA B-frag order (bf16) + transpose rpb ----
struct PrepP {
  const float* wsrc[9];
  const float* rpb[3];
  unsigned short* wdst;
  float* rpbT;
  int do_rpbT;
};

__global__ void prep(PrepP pp) {
  int i = blockIdx.x * 256 + threadIdx.x;
  if (i < 24576) {
    const int off[10] = {0, 1024, 3072, 4096, 5120, 7168, 8192, 12288, 20480, 24576};
    const int SDs[9] = {32, 32, 32, 32, 32, 32, 64, 64, 64};
    int r = 0;
    while (i >= off[r + 1]) ++r;
    int e = i - off[r];
    int j = e & 7, lane = (e >> 3) & 63, blk = e >> 9;
    int KT = SDs[r] >> 4;
    int nt = blk / KT, kk = blk - nt * KT;
    int row = nt * 32 + (lane & 31);
    int col = kk * 16 + (lane >> 5) * 8 + j;
    pp.wdst[i] = f2bf(pp.wsrc[r][row * SDs[r] + col]);
  } else if (pp.do_rpbT) {
    int t = i - 24576;
    if (t < 65536) {
      int hh = t >> 13, rem = t & 8191, key = rem >> 6, q = rem & 63;
      int g = (hh >= 4) ? 2 : (hh >> 1);
      int hl = hh - ((g == 2) ? 4 : g * 2);
      pp.rpbT[t] = pp.rpb[g][(hl * 64 + q) * 128 + key];
    }
  }
}

extern "C" void kernel_launch(void* const* d_in, const int* in_sizes, int n_in,
                              void* d_out, int out_size, void* d_ws, size_t ws_size,
                              hipStream_t stream) {
  (void)in_sizes; (void)n_in; (void)out_size;
  P2 p;
  PrepP pp;
  p.query = (const float*)d_in[0];
  p.keys = (const float*)d_in[1];
  p.km = (const int*)d_in[2];
  const int base[3] = {3, 10, 17};
  unsigned short* wbf = (unsigned short*)d_ws;
  const int woff[9] = {0, 1024, 3072, 4096, 5120, 7168, 8192, 12288, 20480};
  int can_rpbT = ws_size >= (size_t)(49152 + 262144);
  float* rpbT = (float*)((char*)d_ws + 49152);
  for (int g = 0; g < 3; ++g) {
    p.rpb[g] = (const float*)d_in[base[g]];
    p.bq[g] = (const float*)d_in[base[g] + 2];
    p.bkv[g] = (const float*)d_in[base[g] + 4];
    p.bp[g] = (const float*)d_in[base[g] + 6];
    p.wqP[g] = wbf + woff[g * 3];
    p.wkvP[g] = wbf + woff[g * 3 + 1];
    p.wpP[g] = wbf + woff[g * 3 + 2];
    pp.wsrc[g * 3] = (const float*)d_in[base[g] + 1];
    pp.wsrc[g * 3 + 1] = (const float*)d_in[base[g] + 3];
    pp.wsrc[g * 3 + 2] = (const float*)d_in[base[g] + 5];
    pp.rpb[g] = (const float*)d_in[base[g]];
  }
  p.rpbT = can_rpbT ? rpbT : nullptr;
  p.out = (float*)d_out;
  pp.wdst = wbf;
  pp.rpbT = rpbT;
  pp.do_rpbT = can_rpbT;

  prep<<<352, 256, 0, stream>>>(pp);
  msa2<<<2048, 512, 0, stream>>>(p);
}